// Round 1
// baseline (100.014 us; speedup 1.0000x reference)
//
#include <hip/hip_runtime.h>

// TSClusteringLayer: q[n,k] = studentT(sum_f sqrt(sum_t (x[n,t,f]-c[k,t,f])^2)), row-normalized.
// x: (2048,128,32) f32, clusters: (32,128,32) f32, out: (2048,32) f32.
//
// Layout: 256 blocks x 256 threads. Block covers 8 n. Thread tile: 2n x 4k x 4f.
//   tid bits: [2:0]=f_grp (f0=f_grp*4), [5:3]=k_grp (k0=k_grp*4), [7:6]=n_grp (2 n each).
// A wave (64 lanes) covers one n-pair, all 32 k, all 32 f -> f/k reductions are
// pure __shfl_xor within the wave; no LDS, no barriers.

#define T_DIM 128
#define F_DIM 32
#define K_DIM 32
#define TF (T_DIM * F_DIM)

__global__ __launch_bounds__(256, 1) void tscluster_kernel(
    const float* __restrict__ x,
    const float* __restrict__ c,
    float* __restrict__ out)
{
    const int tid   = threadIdx.x;
    const int f_grp = tid & 7;
    const int k_grp = (tid >> 3) & 7;
    const int n_grp = tid >> 6;
    const int f0 = f_grp << 2;
    const int k0 = k_grp << 2;
    const int n0 = (blockIdx.x << 3) + (n_grp << 1);

    const float* xp0 = x + (size_t)n0 * TF + f0;
    const float* xp1 = xp0 + TF;
    const float* cp0 = c + (size_t)k0 * TF + f0;
    const float* cp1 = cp0 + TF;
    const float* cp2 = cp1 + TF;
    const float* cp3 = cp2 + TF;

    float acc[2][4][4];
    #pragma unroll
    for (int a = 0; a < 2; ++a)
        #pragma unroll
        for (int b = 0; b < 4; ++b)
            #pragma unroll
            for (int j = 0; j < 4; ++j)
                acc[a][b][j] = 0.0f;

    #pragma unroll 2
    for (int t = 0; t < T_DIM; ++t) {
        const int off = t * F_DIM;
        const float4 xv0 = *reinterpret_cast<const float4*>(xp0 + off);
        const float4 xv1 = *reinterpret_cast<const float4*>(xp1 + off);
        const float4 cv0 = *reinterpret_cast<const float4*>(cp0 + off);
        const float4 cv1 = *reinterpret_cast<const float4*>(cp1 + off);
        const float4 cv2 = *reinterpret_cast<const float4*>(cp2 + off);
        const float4 cv3 = *reinterpret_cast<const float4*>(cp3 + off);

        const float xs0[4] = {xv0.x, xv0.y, xv0.z, xv0.w};
        const float xs1[4] = {xv1.x, xv1.y, xv1.z, xv1.w};
        const float cs[4][4] = {
            {cv0.x, cv0.y, cv0.z, cv0.w},
            {cv1.x, cv1.y, cv1.z, cv1.w},
            {cv2.x, cv2.y, cv2.z, cv2.w},
            {cv3.x, cv3.y, cv3.z, cv3.w},
        };

        #pragma unroll
        for (int kk = 0; kk < 4; ++kk) {
            #pragma unroll
            for (int j = 0; j < 4; ++j) {
                const float d0 = xs0[j] - cs[kk][j];
                acc[0][kk][j] += d0 * d0;
                const float d1 = xs1[j] - cs[kk][j];
                acc[1][kk][j] += d1 * d1;
            }
        }
    }

    // per-(n,k): partial distance = sum over this thread's 4 f of sqrt(acc)
    float dist[2][4];
    #pragma unroll
    for (int a = 0; a < 2; ++a)
        #pragma unroll
        for (int b = 0; b < 4; ++b)
            dist[a][b] = sqrtf(acc[a][b][0]) + sqrtf(acc[a][b][1]) +
                         sqrtf(acc[a][b][2]) + sqrtf(acc[a][b][3]);

    // reduce over the 8 f_grp lanes (lane bits 0..2)
    #pragma unroll
    for (int off = 1; off < 8; off <<= 1) {
        #pragma unroll
        for (int a = 0; a < 2; ++a)
            #pragma unroll
            for (int b = 0; b < 4; ++b)
                dist[a][b] += __shfl_xor(dist[a][b], off, 64);
    }

    // Student's t (alpha=1): q_un = (1 + d^2)^-1
    float qun[2][4];
    float qs[2];
    #pragma unroll
    for (int a = 0; a < 2; ++a) {
        qs[a] = 0.0f;
        #pragma unroll
        for (int b = 0; b < 4; ++b) {
            qun[a][b] = 1.0f / (1.0f + dist[a][b] * dist[a][b]);
            qs[a] += qun[a][b];
        }
    }

    // reduce denom over the 8 k_grp lanes (lane bits 3..5)
    #pragma unroll
    for (int off = 8; off < 64; off <<= 1) {
        #pragma unroll
        for (int a = 0; a < 2; ++a)
            qs[a] += __shfl_xor(qs[a], off, 64);
    }

    if (f_grp == 0) {
        #pragma unroll
        for (int a = 0; a < 2; ++a) {
            float4 qv;
            qv.x = qun[a][0] / qs[a];
            qv.y = qun[a][1] / qs[a];
            qv.z = qun[a][2] / qs[a];
            qv.w = qun[a][3] / qs[a];
            *reinterpret_cast<float4*>(out + (size_t)(n0 + a) * K_DIM + k0) = qv;
        }
    }
}

extern "C" void kernel_launch(void* const* d_in, const int* in_sizes, int n_in,
                              void* d_out, int out_size, void* d_ws, size_t ws_size,
                              hipStream_t stream) {
    const float* x = (const float*)d_in[0];
    const float* c = (const float*)d_in[1];
    float* out = (float*)d_out;
    // 2048 n / 8 per block = 256 blocks
    tscluster_kernel<<<dim3(256), dim3(256), 0, stream>>>(x, c, out);
}